// Round 11
// baseline (815.220 us; speedup 1.0000x reference)
//
#include <hip/hip_runtime.h>

#define N_TOK 4096
#define DM 256
#define NH 8
#define DK 32
#define SPANMAX 768   // fast-path union-span cap; real spans <= ~540 (2 segments)

using u16 = unsigned short;
using u32 = unsigned int;
using i64 = long long;
typedef float f32x4 __attribute__((ext_vector_type(4)));

__device__ __forceinline__ float bf2f(u16 u){ return __uint_as_float(((u32)u) << 16); }
__device__ __forceinline__ u16 f2bf(float f){
    u32 x = __float_as_uint(f);
    x += 0x7fffu + ((x >> 16) & 1u);
    return (u16)(x >> 16);
}

// ---- per-query segment bounds (batch sorted; int32 or int64 probed) ----
__global__ __launch_bounds__(256)
void bounds_kernel(const void* __restrict__ batch_q, const void* __restrict__ batch_kv,
                   int2* __restrict__ bounds)
{
    int q = blockIdx.x * 256 + threadIdx.x;
    const int* kv32 = (const int*)batch_kv;
    const i64* kv64 = (const i64*)batch_kv;
    bool is64 = (kv32[N_TOK - 1] == 0);
    int s = is64 ? (int)((const i64*)batch_q)[q] : ((const int*)batch_q)[q];
    int lo = 0, hi = N_TOK;
    while (lo < hi){ int m = (lo + hi) >> 1; int v = is64 ? (int)kv64[m] : kv32[m]; if (v < s) lo = m + 1; else hi = m; }
    int lo2 = lo, hi2 = N_TOK;
    while (lo2 < hi2){ int m = (lo2 + hi2) >> 1; int v = is64 ? (int)kv64[m] : kv32[m]; if (v <= s) lo2 = m + 1; else hi2 = m; }
    bounds[q] = make_int2(lo, lo2);
}

// out[r][c] = sum_d x[r][d] * W[c][d] + b[c]
template<int OUT_BF16>
__global__ __launch_bounds__(256)
void proj_kernel(const float* __restrict__ x, const float* __restrict__ W,
                 const float* __restrict__ bias, void* __restrict__ outv)
{
    const int ROWS = 16;
    int row0 = blockIdx.x * ROWS;
    int c = threadIdx.x;
    float acc[ROWS];
    float bv = bias[c];
#pragma unroll
    for (int r = 0; r < ROWS; ++r) acc[r] = bv;
    const float4* Wv = (const float4*)(W + (size_t)c * DM);
    for (int i = 0; i < DM / 4; ++i){
        float4 w = Wv[i];
        int d0 = i * 4;
#pragma unroll
        for (int r = 0; r < ROWS; ++r){
            const float* xr = x + (size_t)(row0 + r) * DM + d0;
            acc[r] += xr[0] * w.x + xr[1] * w.y + xr[2] * w.z + xr[3] * w.w;
        }
    }
#pragma unroll
    for (int r = 0; r < ROWS; ++r){
        size_t idx = (size_t)(row0 + r) * DM + c;
        if (OUT_BF16) ((u16*)outv)[idx] = f2bf(acc[r]);
        else          ((float*)outv)[idx] = acc[r];
    }
}

// Fused K+V projection; writes bf16 K,V in HEAD-MAJOR layout [h][token][32]
// so per-(tile,head) attn blocks read a contiguous span*64B slice.
__global__ __launch_bounds__(256)
void proj_kv_kernel(const float* __restrict__ x, const float* __restrict__ Wk,
                    const float* __restrict__ bk, const float* __restrict__ Wv,
                    const float* __restrict__ bv, u16* __restrict__ Kp,
                    u16* __restrict__ Vp)
{
    const int ROWS = 16;
    int row0 = blockIdx.x * ROWS;
    int c = threadIdx.x;
    int hh = c >> 5, dd = c & 31;     // head-major output index
    float acck[ROWS], accv[ROWS];
    float bkv = bk[c], bvv = bv[c];
#pragma unroll
    for (int r = 0; r < ROWS; ++r){ acck[r] = bkv; accv[r] = bvv; }
    const float4* Wk4 = (const float4*)(Wk + (size_t)c * DM);
    const float4* Wv4 = (const float4*)(Wv + (size_t)c * DM);
    for (int i = 0; i < DM / 4; ++i){
        float4 wk = Wk4[i];
        float4 wv = Wv4[i];
        int d0 = i * 4;
#pragma unroll
        for (int r = 0; r < ROWS; ++r){
            const float* xr = x + (size_t)(row0 + r) * DM + d0;
            float x0 = xr[0], x1 = xr[1], x2 = xr[2], x3 = xr[3];
            acck[r] += x0 * wk.x + x1 * wk.y + x2 * wk.z + x3 * wk.w;
            accv[r] += x0 * wv.x + x1 * wv.y + x2 * wv.z + x3 * wv.w;
        }
    }
#pragma unroll
    for (int r = 0; r < ROWS; ++r){
        size_t idx = ((size_t)hh * N_TOK + (row0 + r)) * DK + dd;
        Kp[idx] = f2bf(acck[r]);
        Vp[idx] = f2bf(accv[r]);
    }
}

// Block = (8-query tile, head h). Fast path (union span <= SPANMAX):
// wave w owns queries 2w,2w+1 end-to-end -> zero barriers. Q in regs,
// contiguous head-major K reads, per-q segment masking (-1e30) handles
// boundary-straddling tiles, NT stores for the full attn rows.
__global__ __launch_bounds__(256)
void attn_fused(const float* __restrict__ Q, const u16* __restrict__ K,
                const u16* __restrict__ V, const int2* __restrict__ bounds,
                float* __restrict__ attn, float* __restrict__ O)
{
    __shared__ float sc[NH][SPANMAX];   // 24 KB; slow path reuses as flat[6144]
    __shared__ float red[4][2];
    __shared__ float osh[DK];

    int tile = blockIdx.x, h = blockIdx.y, tid = threadIdx.x;
    int qbase = tile * 8;
    int klo = bounds[qbase].x;
    int khi = bounds[qbase + 7].y;      // sorted -> max hi over tile
    int span = khi - klo;
    const u16* Kh = K + (size_t)h * N_TOK * DK;
    const u16* Vh = V + (size_t)h * N_TOK * DK;
    const float scale = 0.17677669529663687f;   // 1/sqrt(32)

    if (span <= SPANMAX){
        int w = tid >> 6, lane = tid & 63;
        int q0 = qbase + 2 * w;
        int2 b0 = bounds[q0], b1 = bounds[q0 + 1];
        float q0f[32], q1f[32];
        {
            const float4* qp0 = (const float4*)(Q + (size_t)q0 * DM + h * DK);
            const float4* qp1 = (const float4*)(Q + (size_t)(q0 + 1) * DM + h * DK);
#pragma unroll
            for (int i = 0; i < 8; ++i){
                float4 a = qp0[i], b = qp1[i];
                q0f[4*i]=a.x; q0f[4*i+1]=a.y; q0f[4*i+2]=a.z; q0f[4*i+3]=a.w;
                q1f[4*i]=b.x; q1f[4*i+1]=b.y; q1f[4*i+2]=b.z; q1f[4*i+3]=b.w;
            }
        }
        // scores -> LDS + online (m,l) per q
        float m0 = -1e30f, l0 = 0.f, m1 = -1e30f, l1 = 0.f;
        for (int k = klo + lane; k < khi; k += 64){
            const uint4* kr = (const uint4*)(Kh + (size_t)k * DK);
            float d0 = 0.f, d1 = 0.f;
#pragma unroll
            for (int i = 0; i < 4; ++i){
                uint4 pp = kr[i];
                float f;
                f = bf2f((u16)pp.x);        d0 += q0f[8*i+0]*f; d1 += q1f[8*i+0]*f;
                f = bf2f((u16)(pp.x>>16));  d0 += q0f[8*i+1]*f; d1 += q1f[8*i+1]*f;
                f = bf2f((u16)pp.y);        d0 += q0f[8*i+2]*f; d1 += q1f[8*i+2]*f;
                f = bf2f((u16)(pp.y>>16));  d0 += q0f[8*i+3]*f; d1 += q1f[8*i+3]*f;
                f = bf2f((u16)pp.z);        d0 += q0f[8*i+4]*f; d1 += q1f[8*i+4]*f;
                f = bf2f((u16)(pp.z>>16));  d0 += q0f[8*i+5]*f; d1 += q1f[8*i+5]*f;
                f = bf2f((u16)pp.w);        d0 += q0f[8*i+6]*f; d1 += q1f[8*i+6]*f;
                f = bf2f((u16)(pp.w>>16));  d0 += q0f[8*i+7]*f; d1 += q1f[8*i+7]*f;
            }
            d0 = (k >= b0.x && k < b0.y) ? d0 * scale : -1e30f;
            d1 = (k >= b1.x && k < b1.y) ? d1 * scale : -1e30f;
            sc[2*w  ][k - klo] = d0;
            sc[2*w+1][k - klo] = d1;
            float nm = fmaxf(m0, d0);
            l0 = l0 * __expf(m0 - nm) + __expf(d0 - nm); m0 = nm;
            nm = fmaxf(m1, d1);
            l1 = l1 * __expf(m1 - nm) + __expf(d1 - nm); m1 = nm;
        }
        // 64-lane butterfly merge (wave-private q rows -> no barrier)
#pragma unroll
        for (int off = 32; off; off >>= 1){
            float mo = __shfl_xor(m0, off, 64), lx = __shfl_xor(l0, off, 64);
            float nm = fmaxf(m0, mo);
            l0 = l0 * __expf(m0 - nm) + lx * __expf(mo - nm); m0 = nm;
            mo = __shfl_xor(m1, off, 64); lx = __shfl_xor(l1, off, 64);
            nm = fmaxf(m1, mo);
            l1 = l1 * __expf(m1 - nm) + lx * __expf(mo - nm); m1 = nm;
        }
        float inv0 = (l0 > 0.f) ? (1.f / l0) : 0.f;
        float inv1 = (l1 > 0.f) ? (1.f / l1) : 0.f;

        // row write: probs (back into LDS too) + zeros, all NT
        int tql = klo >> 2, tqh = (khi + 3) >> 2;
        f32x4 z4 = {0.f, 0.f, 0.f, 0.f};
#pragma unroll
        for (int r = 0; r < 2; ++r){
            float mq  = r ? m1 : m0;
            float invq = r ? inv1 : inv0;
            float* srow = sc[2*w + r];
            f32x4* arow4 = (f32x4*)(attn + ((size_t)h * N_TOK + (q0 + r)) * N_TOK);
            for (int t = lane; t < tql; t += 64)
                __builtin_nontemporal_store(z4, arow4 + t);
            for (int t = tqh + lane; t < N_TOK / 4; t += 64)
                __builtin_nontemporal_store(z4, arow4 + t);
            for (int t = tql + lane; t < tqh; t += 64){
                int k0 = 4 * t;
                f32x4 vq;
#pragma unroll
                for (int e = 0; e < 4; ++e){
                    int k = k0 + e;
                    bool in = (k >= klo && k < khi);
                    int idx = k - klo; idx = idx < 0 ? 0 : (idx >= SPANMAX ? SPANMAX - 1 : idx);
                    float p = in ? __expf(srow[idx] - mq) * invq : 0.f;
                    if (in) srow[idx] = p;
                    vq[e] = p;
                }
                __builtin_nontemporal_store(vq, arow4 + t);
            }
        }

        // PV from wave-private LDS probs: lane = (qq, par, d2)
        int d2 = lane & 15, par = (lane >> 4) & 1, qq = lane >> 5;
        float* srow = sc[2*w + qq];
        float a0 = 0.f, a1 = 0.f;
        for (int k = klo + par; k < khi; k += 2){
            u32 pv = *(const u32*)(Vh + (size_t)k * DK + 2 * d2);
            float p = srow[k - klo];
            a0 += p * bf2f((u16)pv);
            a1 += p * bf2f((u16)(pv >> 16));
        }
        a0 += __shfl_xor(a0, 16, 64);
        a1 += __shfl_xor(a1, 16, 64);
        if (par == 0)
            *(float2*)(O + (size_t)(q0 + qq) * DM + h * DK + 2 * d2) = make_float2(a0, a1);
    } else {
        // ---- slow path (span > SPANMAX): per q sequential, block-wide ----
        float* scf = &sc[0][0];          // 6144 floats >= any segment (<=4096)
        for (int qi = 0; qi < 8; ++qi){
            int qg = qbase + qi;
            int2 bq = bounds[qg];
            int lo = bq.x, hi = bq.y;
            float qf[32];
            const float4* qp = (const float4*)(Q + (size_t)qg * DM + h * DK);
#pragma unroll
            for (int i = 0; i < 8; ++i){
                float4 v = qp[i];
                qf[4*i]=v.x; qf[4*i+1]=v.y; qf[4*i+2]=v.z; qf[4*i+3]=v.w;
            }
            // pass 1: stats
            float m = -1e30f, l = 0.f;
            for (int k = lo + tid; k < hi; k += 256){
                const uint4* kr = (const uint4*)(Kh + (size_t)k * DK);
                float dot = 0.f;
#pragma unroll
                for (int i = 0; i < 4; ++i){
                    uint4 pp = kr[i];
                    dot += qf[8*i+0]*bf2f((u16)pp.x) + qf[8*i+1]*bf2f((u16)(pp.x>>16));
                    dot += qf[8*i+2]*bf2f((u16)pp.y) + qf[8*i+3]*bf2f((u16)(pp.y>>16));
                    dot += qf[8*i+4]*bf2f((u16)pp.z) + qf[8*i+5]*bf2f((u16)(pp.z>>16));
                    dot += qf[8*i+6]*bf2f((u16)pp.w) + qf[8*i+7]*bf2f((u16)(pp.w>>16));
                }
                dot *= scale;
                float nm = fmaxf(m, dot);
                l = l * __expf(m - nm) + __expf(dot - nm); m = nm;
            }
#pragma unroll
            for (int off = 32; off; off >>= 1){
                float mo = __shfl_xor(m, off, 64), lx = __shfl_xor(l, off, 64);
                float nm = fmaxf(m, mo);
                l = l * __expf(m - nm) + lx * __expf(mo - nm); m = nm;
            }
            if ((tid & 63) == 0){ red[tid >> 6][0] = m; red[tid >> 6][1] = l; }
            if (tid < DK) osh[tid] = 0.f;
            __syncthreads();
            float fm = -1e30f, fl = 0.f;
#pragma unroll
            for (int i2 = 0; i2 < 4; ++i2){
                float mo = red[i2][0], lx = red[i2][1];
                float nm = fmaxf(fm, mo);
                fl = fl * __expf(fm - nm) + lx * __expf(mo - nm); fm = nm;
            }
            float inv = (fl > 0.f) ? (1.f / fl) : 0.f;
            // pass 2: recompute -> probs (LDS + NT global)
            float* arow = attn + ((size_t)h * N_TOK + qg) * N_TOK;
            for (int k = lo + tid; k < hi; k += 256){
                const uint4* kr = (const uint4*)(Kh + (size_t)k * DK);
                float dot = 0.f;
#pragma unroll
                for (int i = 0; i < 4; ++i){
                    uint4 pp = kr[i];
                    dot += qf[8*i+0]*bf2f((u16)pp.x) + qf[8*i+1]*bf2f((u16)(pp.x>>16));
                    dot += qf[8*i+2]*bf2f((u16)pp.y) + qf[8*i+3]*bf2f((u16)(pp.y>>16));
                    dot += qf[8*i+4]*bf2f((u16)pp.z) + qf[8*i+5]*bf2f((u16)(pp.z>>16));
                    dot += qf[8*i+6]*bf2f((u16)pp.w) + qf[8*i+7]*bf2f((u16)(pp.w>>16));
                }
                float p = __expf(dot * scale - fm) * inv;
                scf[k - lo] = p;
                __builtin_nontemporal_store(p, &arow[k]);
            }
            // zeros outside
            int tql = lo >> 2, tqh2 = (hi + 3) >> 2;
            f32x4 z4 = {0.f, 0.f, 0.f, 0.f};
            for (int t = tid; t < tql; t += 256)
                __builtin_nontemporal_store(z4, (f32x4*)arow + t);
            for (int t = tqh2 + tid; t < N_TOK / 4; t += 256)
                __builtin_nontemporal_store(z4, (f32x4*)arow + t);
            for (int k = 4 * tql + tid; k < lo; k += 256)
                __builtin_nontemporal_store(0.f, &arow[k]);
            for (int k = hi + tid; k < 4 * tqh2; k += 256)
                __builtin_nontemporal_store(0.f, &arow[k]);
            __syncthreads();
            // PV from LDS probs (already normalized)
            int d = tid & 31, grp = tid >> 5;
            float acc = 0.f;
            for (int k = lo + grp; k < hi; k += 8)
                acc += scf[k - lo] * bf2f(Vh[(size_t)k * DK + d]);
            atomicAdd(&osh[d], acc);
            __syncthreads();
            if (tid < DK) O[(size_t)qg * DM + h * DK + tid] = osh[tid];
            __syncthreads();
        }
    }
}

extern "C" void kernel_launch(void* const* d_in, const int* in_sizes, int n_in,
                              void* d_out, int out_size, void* d_ws, size_t ws_size,
                              hipStream_t stream)
{
    const float* x_q  = (const float*)d_in[0];
    const float* x_kv = (const float*)d_in[1];
    const void* batch_q  = d_in[2];
    const void* batch_kv = d_in[3];
    const float* Wq = (const float*)d_in[4];
    const float* bq = (const float*)d_in[5];
    const float* Wk = (const float*)d_in[6];
    const float* bk = (const float*)d_in[7];
    const float* Wv = (const float*)d_in[8];
    const float* bv = (const float*)d_in[9];
    const float* Wo = (const float*)d_in[10];
    const float* bo = (const float*)d_in[11];

    char* ws = (char*)d_ws;
    float* Q  = (float*)ws;                                 // 4 MB fp32
    u16*   Kp = (u16*)(ws + (size_t)4 * 1024 * 1024);       // 2 MB bf16, head-major
    u16*   Vp = (u16*)(ws + (size_t)6 * 1024 * 1024);       // 2 MB bf16, head-major
    float* O  = (float*)(ws + (size_t)8 * 1024 * 1024);     // 4 MB fp32
    int2* bounds = (int2*)(ws + (size_t)12 * 1024 * 1024);  // 32 KB

    float* out  = (float*)d_out;                            // [4096,256] fp32
    float* attn = out + (size_t)N_TOK * DM;                 // [8,4096,4096] fp32

    bounds_kernel<<<N_TOK / 256, 256, 0, stream>>>(batch_q, batch_kv, bounds);
    proj_kernel<0><<<N_TOK/16, 256, 0, stream>>>(x_q,  Wq, bq, Q);
    proj_kv_kernel<<<N_TOK/16, 256, 0, stream>>>(x_kv, Wk, bk, Wv, bv, Kp, Vp);
    attn_fused<<<dim3(N_TOK/8, NH), 256, 0, stream>>>(Q, Kp, Vp, bounds, attn, O);
    proj_kernel<0><<<N_TOK/16, 256, 0, stream>>>((const float*)O, Wo, bo, out);
}

// Round 12
// 703.460 us; speedup vs baseline: 1.1589x; 1.1589x over previous
//
#include <hip/hip_runtime.h>

#define N_TOK 4096
#define DM 256
#define NH 8
#define DK 32

using u16 = unsigned short;
using u32 = unsigned int;
using i64 = long long;
typedef float f32x4 __attribute__((ext_vector_type(4)));

__device__ __forceinline__ float bf2f(u16 u){ return __uint_as_float(((u32)u) << 16); }
__device__ __forceinline__ u16 f2bf(float f){
    u32 x = __float_as_uint(f);
    x += 0x7fffu + ((x >> 16) & 1u);
    return (u16)(x >> 16);
}

// ---- per-query segment bounds (batch sorted; int32 or int64 probed) ----
__global__ __launch_bounds__(256)
void bounds_kernel(const void* __restrict__ batch_q, const void* __restrict__ batch_kv,
                   int2* __restrict__ bounds)
{
    int q = blockIdx.x * 256 + threadIdx.x;
    const int* kv32 = (const int*)batch_kv;
    const i64* kv64 = (const i64*)batch_kv;
    bool is64 = (kv32[N_TOK - 1] == 0);
    int s = is64 ? (int)((const i64*)batch_q)[q] : ((const int*)batch_q)[q];
    int lo = 0, hi = N_TOK;
    while (lo < hi){ int m = (lo + hi) >> 1; int v = is64 ? (int)kv64[m] : kv32[m]; if (v < s) lo = m + 1; else hi = m; }
    int lo2 = lo, hi2 = N_TOK;
    while (lo2 < hi2){ int m = (lo2 + hi2) >> 1; int v = is64 ? (int)kv64[m] : kv32[m]; if (v <= s) lo2 = m + 1; else hi2 = m; }
    bounds[q] = make_int2(lo, lo2);
}

// out[r][c] = sum_d x[r][d] * W[c][d] + b[c]
template<int OUT_BF16>
__global__ __launch_bounds__(256)
void proj_kernel(const float* __restrict__ x, const float* __restrict__ W,
                 const float* __restrict__ bias, void* __restrict__ outv)
{
    const int ROWS = 16;
    int row0 = blockIdx.x * ROWS;
    int c = threadIdx.x;
    float acc[ROWS];
    float bv = bias[c];
#pragma unroll
    for (int r = 0; r < ROWS; ++r) acc[r] = bv;
    const float4* Wv = (const float4*)(W + (size_t)c * DM);
    for (int i = 0; i < DM / 4; ++i){
        float4 w = Wv[i];
        int d0 = i * 4;
#pragma unroll
        for (int r = 0; r < ROWS; ++r){
            const float* xr = x + (size_t)(row0 + r) * DM + d0;
            acc[r] += xr[0] * w.x + xr[1] * w.y + xr[2] * w.z + xr[3] * w.w;
        }
    }
#pragma unroll
    for (int r = 0; r < ROWS; ++r){
        size_t idx = (size_t)(row0 + r) * DM + c;
        if (OUT_BF16) ((u16*)outv)[idx] = f2bf(acc[r]);
        else          ((float*)outv)[idx] = acc[r];
    }
}

// Fused K+V projection; writes bf16 K,V in HEAD-MAJOR layout [h][token][32]
// so attn blocks (fixed h) read dense contiguous 64B/token slices.
__global__ __launch_bounds__(256)
void proj_kv_kernel(const float* __restrict__ x, const float* __restrict__ Wk,
                    const float* __restrict__ bk, const float* __restrict__ Wv,
                    const float* __restrict__ bv, u16* __restrict__ Kp,
                    u16* __restrict__ Vp)
{
    const int ROWS = 16;
    int row0 = blockIdx.x * ROWS;
    int c = threadIdx.x;
    int hh = c >> 5, dd = c & 31;     // head-major output index
    float acck[ROWS], accv[ROWS];
    float bkv = bk[c], bvv = bv[c];
#pragma unroll
    for (int r = 0; r < ROWS; ++r){ acck[r] = bkv; accv[r] = bvv; }
    const float4* Wk4 = (const float4*)(Wk + (size_t)c * DM);
    const float4* Wv4 = (const float4*)(Wv + (size_t)c * DM);
    for (int i = 0; i < DM / 4; ++i){
        float4 wk = Wk4[i];
        float4 wv = Wv4[i];
        int d0 = i * 4;
#pragma unroll
        for (int r = 0; r < ROWS; ++r){
            const float* xr = x + (size_t)(row0 + r) * DM + d0;
            float x0 = xr[0], x1 = xr[1], x2 = xr[2], x3 = xr[3];
            acck[r] += x0 * wk.x + x1 * wk.y + x2 * wk.z + x3 * wk.w;
            accv[r] += x0 * wv.x + x1 * wv.y + x2 * wv.z + x3 * wv.w;
        }
    }
#pragma unroll
    for (int r = 0; r < ROWS; ++r){
        size_t idx = ((size_t)hh * N_TOK + (row0 + r)) * DK + dd;
        Kp[idx] = f2bf(acck[r]);
        Vp[idx] = f2bf(accv[r]);
    }
}

// R9 chassis: one block per (query q, head h), 32768 blocks. Only change:
// K/V are head-major -> score loop reads Kh+k*64B dense; PV V-loads dense.
__global__ __launch_bounds__(256)
void attn_kernel(const float* __restrict__ Q, const u16* __restrict__ K,
                 const u16* __restrict__ V, const int2* __restrict__ bounds,
                 float* __restrict__ attn, float* __restrict__ O)
{
    __shared__ float sc[N_TOK];    // unnormalized probs
    __shared__ float qs[DK];
    __shared__ float red[8];
    __shared__ float Osh[DK];

    int q = blockIdx.x, h = blockIdx.y, tid = threadIdx.x;
    int2 bnd = bounds[q];
    const int lo = bnd.x, hi = bnd.y;
    const u16* Kh = K + (size_t)h * N_TOK * DK;
    const u16* Vh = V + (size_t)h * N_TOK * DK;

    if (tid < DK){ qs[tid] = Q[(size_t)q * DM + h * DK + tid]; Osh[tid] = 0.f; }
    __syncthreads();

    const float scale = 0.17677669529663687f;   // 1/sqrt(32)

    // ---- scores + local max ----
    float lmax = -1e30f;
    for (int k = lo + tid; k < hi; k += 256){
        const uint4* kr = (const uint4*)(Kh + (size_t)k * DK);   // 64B dense
        float dot = 0.f;
#pragma unroll
        for (int i = 0; i < 4; ++i){
            uint4 p = kr[i];
            dot += qs[i*8+0]*bf2f((u16)p.x) + qs[i*8+1]*bf2f((u16)(p.x>>16));
            dot += qs[i*8+2]*bf2f((u16)p.y) + qs[i*8+3]*bf2f((u16)(p.y>>16));
            dot += qs[i*8+4]*bf2f((u16)p.z) + qs[i*8+5]*bf2f((u16)(p.z>>16));
            dot += qs[i*8+6]*bf2f((u16)p.w) + qs[i*8+7]*bf2f((u16)(p.w>>16));
        }
        dot *= scale;
        sc[k - lo] = dot;
        lmax = fmaxf(lmax, dot);
    }
#pragma unroll
    for (int off = 32; off; off >>= 1) lmax = fmaxf(lmax, __shfl_xor(lmax, off, 64));
    if ((tid & 63) == 0) red[tid >> 6] = lmax;
    __syncthreads();
    float m = fmaxf(fmaxf(red[0], red[1]), fmaxf(red[2], red[3]));

    // ---- exp + local sum ----
    float lsum = 0.f;
    for (int k = lo + tid; k < hi; k += 256){
        float p = __expf(sc[k - lo] - m);
        sc[k - lo] = p;
        lsum += p;
    }
#pragma unroll
    for (int off = 32; off; off >>= 1) lsum += __shfl_xor(lsum, off, 64);
    if ((tid & 63) == 0) red[4 + (tid >> 6)] = lsum;
    __syncthreads();
    float sum = red[4] + red[5] + red[6] + red[7];
    float inv = (sum > 0.f) ? (1.0f / sum) : 0.f;

    // ---- PV first (loads), then the bulk store stream ----
    int d2 = tid & 15;
    int g  = tid >> 4;
    float p0 = 0.f, p1 = 0.f;
    for (int k = lo + g; k < hi; k += 16){
        u32 pv = *(const u32*)(Vh + (size_t)k * DK + 2 * d2);    // dense 64B/k
        float p = sc[k - lo];
        p0 += p * bf2f((u16)pv);
        p1 += p * bf2f((u16)(pv >> 16));
    }
    p0 += __shfl_xor(p0, 16, 64); p0 += __shfl_xor(p0, 32, 64);
    p1 += __shfl_xor(p1, 16, 64); p1 += __shfl_xor(p1, 32, 64);
    if ((tid & 63) < 16){
        atomicAdd(&Osh[2 * d2 + 0], p0);
        atomicAdd(&Osh[2 * d2 + 1], p1);
    }

    // ---- write full attn row (zeros outside segment), nontemporal float4 ----
    f32x4* arow4 = (f32x4*)(attn + ((size_t)h * N_TOK + q) * N_TOK);
#pragma unroll
    for (int i = 0; i < N_TOK / 1024; ++i){
        int t = i * 256 + tid;
        int k0 = 4 * t;
        f32x4 w;
        w.x = (k0 + 0 >= lo && k0 + 0 < hi) ? sc[k0 + 0 - lo] * inv : 0.f;
        w.y = (k0 + 1 >= lo && k0 + 1 < hi) ? sc[k0 + 1 - lo] * inv : 0.f;
        w.z = (k0 + 2 >= lo && k0 + 2 < hi) ? sc[k0 + 2 - lo] * inv : 0.f;
        w.w = (k0 + 3 >= lo && k0 + 3 < hi) ? sc[k0 + 3 - lo] * inv : 0.f;
        __builtin_nontemporal_store(w, &arow4[t]);
    }

    __syncthreads();
    if (tid < DK) O[(size_t)q * DM + h * DK + tid] = Osh[tid] * inv;
}

extern "C" void kernel_launch(void* const* d_in, const int* in_sizes, int n_in,
                              void* d_out, int out_size, void* d_ws, size_t ws_size,
                              hipStream_t stream)
{
    const float* x_q  = (const float*)d_in[0];
    const float* x_kv = (const float*)d_in[1];
    const void* batch_q  = d_in[2];
    const void* batch_kv = d_in[3];
    const float* Wq = (const float*)d_in[4];
    const float* bq = (const float*)d_in[5];
    const float* Wk = (const float*)d_in[6];
    const float* bk = (const float*)d_in[7];
    const float* Wv = (const float*)d_in[8];
    const float* bv = (const float*)d_in[9];
    const float* Wo = (const float*)d_in[10];
    const float* bo = (const float*)d_in[11];

    char* ws = (char*)d_ws;
    float* Q  = (float*)ws;                                 // 4 MB fp32
    u16*   Kp = (u16*)(ws + (size_t)4 * 1024 * 1024);       // 2 MB bf16, head-major
    u16*   Vp = (u16*)(ws + (size_t)6 * 1024 * 1024);       // 2 MB bf16, head-major
    float* O  = (float*)(ws + (size_t)8 * 1024 * 1024);     // 4 MB fp32
    int2* bounds = (int2*)(ws + (size_t)12 * 1024 * 1024);  // 32 KB

    float* out  = (float*)d_out;                            // [4096,256] fp32
    float* attn = out + (size_t)N_TOK * DM;                 // [8,4096,4096] fp32

    bounds_kernel<<<N_TOK / 256, 256, 0, stream>>>(batch_q, batch_kv, bounds);
    proj_kernel<0><<<N_TOK/16, 256, 0, stream>>>(x_q,  Wq, bq, Q);
    proj_kv_kernel<<<N_TOK/16, 256, 0, stream>>>(x_kv, Wk, bk, Wv, bv, Kp, Vp);
    attn_kernel<<<dim3(N_TOK, NH), 256, 0, stream>>>(Q, Kp, Vp, bounds, attn, O);
    proj_kernel<0><<<N_TOK/16, 256, 0, stream>>>((const float*)O, Wo, bo, out);
}